// Round 7
// baseline (502.010 us; speedup 1.0000x reference)
//
#include <hip/hip_runtime.h>
#include <hip/hip_fp16.h>

// GraphEmbedding2: 3-layer GCN (DGL GraphConv, norm='both') + per-graph mean pooling.
// N=50000 nodes, E=600000 edges, d=128, G=64 graphs.
// fp16 gather operands (R6); LDS-histogram degrees + LDS-cursor CSR fill (R5/R8);
// MFMA fp16-in/fp32-acc transposed roles (R9/R15); pool-fused layer 3 (R15);
// 32-edge-round agg (R17); prep folded into scan (R20).
// R21: (a) hist ranges 4->2 (HR2=2, 25K nodes/range, 50KB LDS): each edge array read
// 2x instead of 4x (19.2->9.6MB hist traffic, 512->256 blocks). Cursor/fill side KEEPS
// the 4x12500 window layout (fill2 untouched — R14: fill2 is launch-parallelism-bound);
// merge/scan-phase-B reindex only (cursors are per-node, layouts decouple).
// (b) k_finalize folded into k_gemm_pool via last-block ticket (threadfence + device
// atomic; last block does G*DIM divisions + binary-search counts). -1 dispatch.
// Agg wall (3x ~38us) is line-service-capped: R17 doubled lines-in-flight -> neutral;
// R18 locality slicing -> negative; ~4 TB/s random-64B-line service is the HW number.
// Reverted-for-cause: R7/R16 fusion (lost gather parallelism), R11 range passes,
// R13 HIST_S=32, R18 quartered gather, R19 global-atomic CSR build (k_deg 50us).

#define DIM 128
#define GRAPHS 64

typedef _Float16 half8 __attribute__((ext_vector_type(8)));
typedef _Float16 half4 __attribute__((ext_vector_type(4)));
typedef float floatx4 __attribute__((ext_vector_type(4)));

// hist/merge layout (R21): 2 ranges x 25000 nodes
#define HR2 2
#define NP2 25000
#define LW2 (NP2 / 2)      // 12500 u32 words, 50 KB LDS
#define HIST_S 64
// cursor/fill layout (unchanged): 4 windows x 12500 nodes
#define FILL_R 4
#define NPR 12500

__global__ __launch_bounds__(256) void k_hist(const int* __restrict__ src,
                                              const int* __restrict__ dst,
                                              unsigned* __restrict__ partial, int E) {
    __shared__ __align__(16) unsigned hist[LW2];
    int b = blockIdx.x;
    int a = b / (HR2 * HIST_S);          // 0: src, 1: dst
    int r = (b / HIST_S) % HR2;          // node range (25000 wide)
    int s = b % HIST_S;                  // edge slice
    const int* arr = a ? dst : src;
    for (int i = threadIdx.x; i < LW2; i += 256) hist[i] = 0;
    __syncthreads();
    int chunk = (E + HIST_S - 1) / HIST_S;
    int e0 = s * chunk;
    int e1 = min(e0 + chunk, E);
    unsigned base = (unsigned)(r * NP2);
    for (int i = e0 + threadIdx.x; i < e1; i += 256) {
        unsigned n = (unsigned)arr[i] - base;
        if (n < NP2) atomicAdd(&hist[n >> 1], 1u << ((n & 1) * 16));
    }
    __syncthreads();
    uint2* outp = (uint2*)(partial + ((size_t)(a * HR2 + r) * HIST_S + s) * LW2);
    const uint2* h2 = (const uint2*)hist;
    for (int i = threadIdx.x; i < LW2 / 2; i += 256) outp[i] = h2[i];
}

// ---------------------------------------------------------------- merge + block sums
// Blocks [0, nb): dst — nd, inc, per-256-node bsum. Blocks [nb, 2nb): src — ns.
__global__ __launch_bounds__(256) void k_hist_merge(const unsigned* __restrict__ partial,
                                                    float* __restrict__ ns,
                                                    float* __restrict__ nd,
                                                    int* __restrict__ inc,
                                                    int* __restrict__ bsum, int N) {
    __shared__ int sred[256];
    int nb = (N + 255) / 256;
    int isDst = (blockIdx.x < nb) ? 1 : 0;
    int cb = isDst ? blockIdx.x : blockIdx.x - nb;
    int n = cb * 256 + threadIdx.x;
    int deg = 0;
    if (n < N) {
        int a = isDst ? 1 : 0;
        int r = n / NP2;
        int w = (n % NP2) >> 1;
        int field = (n & 1) * 16;
        const unsigned* p = partial + ((size_t)(a * HR2 + r) * HIST_S) * LW2 + w;
        unsigned sum = 0;
#pragma unroll
        for (int s = 0; s < HIST_S; ++s) sum += p[(size_t)s * LW2];
        deg = (int)((sum >> field) & 0xFFFFu);
        float nrm = rsqrtf(fmaxf((float)deg, 1.0f));
        if (isDst) { nd[n] = nrm; inc[n] = deg; }
        else       { ns[n] = nrm; }
    }
    if (isDst) {
        sred[threadIdx.x] = deg;
        __syncthreads();
        for (int off = 128; off > 0; off >>= 1) {
            if (threadIdx.x < off) sred[threadIdx.x] += sred[threadIdx.x + off];
            __syncthreads();
        }
        if (threadIdx.x == 0) bsum[cb] = sred[0];
    }
}

// ---------------------------------------------------------------- scan + cursors + prep (folded)
// Blocks [0, nb): block-sum scan -> row_ptr scan -> per-(window,slice) cursors;
// block 0 zeroes gsum + done. Blocks [nb, nb+prepBlocks): prep role.
__global__ __launch_bounds__(256) void k_scan_prep(
    const int* __restrict__ inc, const int* __restrict__ bsum,
    const unsigned* __restrict__ partial, int* __restrict__ row_ptr,
    int* __restrict__ cur, float* __restrict__ gsum, int* __restrict__ done,
    const float4* __restrict__ h, const float* __restrict__ ns,
    uint2* __restrict__ A, const float* __restrict__ W1,
    const float* __restrict__ W2, const float* __restrict__ W3,
    _Float16* __restrict__ Wt1, _Float16* __restrict__ Wt2,
    _Float16* __restrict__ Wt3, int N) {
    __shared__ int sb[256];
    __shared__ int s[256];
    __shared__ int exs[256];
    int nb = (N + 255) / 256;
    int t = threadIdx.x;

    if (blockIdx.x >= nb) {
        // ---- prep role
        int i = (blockIdx.x - nb) * 256 + t;
        int nf4 = N * 32;
        if (i < nf4) {
            int n = i >> 5;
            float sc = ns[n];
            float4 v = h[i];
            __half2 p0 = __floats2half2_rn(v.x * sc, v.y * sc);
            __half2 p1 = __floats2half2_rn(v.z * sc, v.w * sc);
            uint2 o;
            o.x = *(unsigned*)&p0;
            o.y = *(unsigned*)&p1;
            A[i] = o;
        } else {
            int j = i - nf4;               // 0 .. 3*16384-1
            if (j < 3 * 16384) {
                int which = j >> 14;
                int local = j & 16383;
                int k = local >> 7;
                int n = local & 127;
                const float* W = (which == 0) ? W1 : (which == 1) ? W2 : W3;
                _Float16* Wt = (which == 0) ? Wt1 : (which == 1) ? Wt2 : Wt3;
                Wt[(size_t)n * DIM + k] = (_Float16)W[local];
            }
        }
        return;
    }

    // ---- scan role: phase 0 — exclusive-scan block sums
    int bv = (t < nb) ? bsum[t] : 0;
    sb[t] = bv;
    __syncthreads();
    for (int off = 1; off < 256; off <<= 1) {
        int u = (t >= off) ? sb[t - off] : 0;
        __syncthreads();
        sb[t] += u;
        __syncthreads();
    }
    int excl = sb[t] - bv;
    __syncthreads();
    sb[t] = excl;
    __syncthreads();
    int blockBase = sb[blockIdx.x];

    // phase A: local scan of inc
    int B = blockIdx.x * 256;
    int i = B + t;
    int v = (i < N) ? inc[i] : 0;
    s[t] = v;
    __syncthreads();
    for (int off = 1; off < 256; off <<= 1) {
        int u = (t >= off) ? s[t - off] : 0;
        __syncthreads();
        s[t] += u;
        __syncthreads();
    }
    int ex = blockBase + s[t] - v;  // global exclusive prefix
    exs[t] = ex;
    if (i < N) row_ptr[i] = ex;
    if (i == N - 1) row_ptr[N] = ex + v;
    if (blockIdx.x == 0) {
        for (int j = t; j < GRAPHS * DIM; j += 256) gsum[j] = 0.0f;
        if (t == 0) done[0] = 0;
    }
    __syncthreads();

    // phase B: per-(window,slice) cursors. dst histogram lives in HR2 layout;
    // cursors use FILL_R x NPR windows (fill2's layout). Per-node counters decouple.
    if (t < 128) {
        int n0 = B + 2 * t;
        if (n0 < N) {
            int r2 = n0 / NP2;
            int w2 = (n0 % NP2) >> 1;
            const unsigned* p = partial + ((size_t)(HR2 + r2) * HIST_S) * LW2 + w2;
            int r4 = n0 / NPR;
            int wf = (n0 % NPR) >> 1;
            int run0 = exs[2 * t];
            int run1 = exs[2 * t + 1];
            int* c = cur + (size_t)r4 * HIST_S * NPR + 2 * wf;
#pragma unroll
            for (int sl = 0; sl < HIST_S; ++sl) {
                c[(size_t)sl * NPR + 0] = run0;
                c[(size_t)sl * NPR + 1] = run1;
                unsigned hv = p[(size_t)sl * LW2];
                run0 += (int)(hv & 0xFFFFu);
                run1 += (int)(hv >> 16);
            }
        }
    }
}

// ---------------------------------------------------------------- CSR fill (LDS cursors)
__global__ __launch_bounds__(256) void k_fill2(const int* __restrict__ src,
                                               const int* __restrict__ dst,
                                               const int* __restrict__ cur,
                                               int* __restrict__ csr, int E) {
    __shared__ __align__(16) int lcur[NPR];   // 50 KB
    int r = blockIdx.x / HIST_S;
    int s = blockIdx.x % HIST_S;
    const int4* cs4 = (const int4*)(cur + (size_t)(r * HIST_S + s) * NPR);
    int4* l4 = (int4*)lcur;
    for (int i = threadIdx.x; i < NPR / 4; i += 256) l4[i] = cs4[i];
    __syncthreads();
    int chunk = (E + HIST_S - 1) / HIST_S;
    int e0 = s * chunk;
    int e1 = min(e0 + chunk, E);
    unsigned base = (unsigned)(r * NPR);
    for (int i = e0 + threadIdx.x; i < e1; i += 256) {
        unsigned d = (unsigned)dst[i] - base;
        if (d < NPR) {
            int p = atomicAdd(&lcur[d], 1);   // LDS atomic
            csr[p] = src[i];
        }
    }
}

// ---------------------------------------------------------------- aggregation (R17 form)
// One wave per node (50K waves). 32-edge rounds: 16 lanes x 16B cover one 256B row ->
// 4 rows per load instruction, 8 loads = 32 edges in flight. Indices: 1 VMEM load of
// 32 idx by lane&31 + shfl broadcast. Epilogue: shfl_xor(16/32) reduce, uint4 stores.
__global__ __launch_bounds__(256) void k_agg(const uint4* __restrict__ A,
                                             const int* __restrict__ row_ptr,
                                             const int* __restrict__ csr,
                                             const float* __restrict__ nd,
                                             uint4* __restrict__ Bh, int N) {
    int gtid = blockIdx.x * blockDim.x + threadIdx.x;
    int node = gtid >> 6;
    int lane = threadIdx.x & 63;
    if (node >= N) return;
    int e0 = row_ptr[node];
    int e1 = row_ptr[node + 1];
    int grp = lane >> 4;     // edge sub-slot within a 4-edge load row-group
    int l16 = lane & 15;     // 16-byte slot within 256B row
    float acc[8];
#pragma unroll
    for (int k = 0; k < 8; ++k) acc[k] = 0.0f;

    for (int base = e0; base < e1; base += 32) {
        int vl = csr[min(base + (lane & 31), e1 - 1)];   // lanes 0-31 hold 32 indices
        uint4 u[8];
#pragma unroll
        for (int j = 0; j < 8; ++j) {
            int idx = __shfl(vl, 4 * j + grp);
            u[j] = A[(size_t)idx * 16 + l16];
        }
#pragma unroll
        for (int j = 0; j < 8; ++j) {
            if (base + 4 * j + grp < e1) {
                __half2 h0 = *(__half2*)&u[j].x;
                __half2 h1 = *(__half2*)&u[j].y;
                __half2 h2 = *(__half2*)&u[j].z;
                __half2 h3 = *(__half2*)&u[j].w;
                float2 f0 = __half22float2(h0);
                float2 f1 = __half22float2(h1);
                float2 f2 = __half22float2(h2);
                float2 f3 = __half22float2(h3);
                acc[0] += f0.x; acc[1] += f0.y;
                acc[2] += f1.x; acc[3] += f1.y;
                acc[4] += f2.x; acc[5] += f2.y;
                acc[6] += f3.x; acc[7] += f3.y;
            }
        }
    }

#pragma unroll
    for (int k = 0; k < 8; ++k) {
        float v = acc[k];
        v += __shfl_xor(v, 16);
        v += __shfl_xor(v, 32);
        acc[k] = v;
    }

    if (grp == 0) {
        float s = nd[node];
        __half2 p0 = __floats2half2_rn(acc[0] * s, acc[1] * s);
        __half2 p1 = __floats2half2_rn(acc[2] * s, acc[3] * s);
        __half2 p2 = __floats2half2_rn(acc[4] * s, acc[5] * s);
        __half2 p3 = __floats2half2_rn(acc[6] * s, acc[7] * s);
        uint4 o;
        o.x = *(unsigned*)&p0;
        o.y = *(unsigned*)&p1;
        o.z = *(unsigned*)&p2;
        o.w = *(unsigned*)&p3;
        Bh[(size_t)node * 16 + l16] = o;
    }
}

// ---------------------------------------------------------------- GEMM on matrix cores (R15 transposed roles)
template <bool SCALE_NS>
__global__ __launch_bounds__(256) void k_gemm_t(
    const _Float16* __restrict__ Bin, const _Float16* __restrict__ Wt,
    const float* __restrict__ bias, const float* __restrict__ ns,
    _Float16* __restrict__ Xout, int N) {
    int tid = threadIdx.x;
    int wave = tid >> 6;
    int lane = tid & 63;
    int quad = lane >> 4;
    int l16 = lane & 15;
    int node = blockIdx.x * 64 + wave * 16 + l16;

    half8 b[4];
#pragma unroll
    for (int q = 0; q < 4; ++q) {
        if (node < N) {
            b[q] = *(const half8*)&Bin[(size_t)node * DIM + q * 32 + quad * 8];
        } else {
            b[q] = half8{0, 0, 0, 0, 0, 0, 0, 0};
        }
    }

    floatx4 acc[8];
#pragma unroll
    for (int c = 0; c < 8; ++c) acc[c] = floatx4{0.f, 0.f, 0.f, 0.f};

#pragma unroll
    for (int c = 0; c < 8; ++c) {
#pragma unroll
        for (int q = 0; q < 4; ++q) {
            half8 a = *(const half8*)&Wt[(size_t)(c * 16 + l16) * DIM + q * 32 + quad * 8];
            acc[c] = __builtin_amdgcn_mfma_f32_16x16x32_f16(a, b[q], acc[c], 0, 0, 0);
        }
    }

    if (node < N) {
        float s = SCALE_NS ? ns[node] : 1.0f;
#pragma unroll
        for (int c = 0; c < 8; ++c) {
            float4 b4 = *(const float4*)&bias[c * 16 + quad * 4];
            half4 o;
            o[0] = (_Float16)(fmaxf(acc[c][0] + b4.x, 0.0f) * s);
            o[1] = (_Float16)(fmaxf(acc[c][1] + b4.y, 0.0f) * s);
            o[2] = (_Float16)(fmaxf(acc[c][2] + b4.z, 0.0f) * s);
            o[3] = (_Float16)(fmaxf(acc[c][3] + b4.w, 0.0f) * s);
            *(half4*)&Xout[(size_t)node * DIM + c * 16 + quad * 4] = o;
        }
    }
}

// ---------------------------------------------------------------- layer-3 GEMM + pooling + finalize
// Pool epilogue from fp32 acc (R15). R21: last-block ticket finalizes (divisions +
// binary-search counts) — k_finalize dispatch eliminated.
#define PBINS 8
__global__ __launch_bounds__(256) void k_gemm_pool(
    const _Float16* __restrict__ Bin, const _Float16* __restrict__ Wt,
    const float* __restrict__ bias, const int* __restrict__ gid,
    float* __restrict__ gsum, int* __restrict__ done,
    float* __restrict__ out, int N) {
    __shared__ float lsum[PBINS * DIM];   // 4 KB
    __shared__ int lastFlag;
    int tid = threadIdx.x;
    for (int i = tid; i < PBINS * DIM; i += 256) lsum[i] = 0.0f;
    int wave = tid >> 6;
    int lane = tid & 63;
    int quad = lane >> 4;
    int l16 = lane & 15;
    int r0 = blockIdx.x * 64;
    int node = r0 + wave * 16 + l16;
    int nodec = min(node, N - 1);

    half8 b[4];
#pragma unroll
    for (int q = 0; q < 4; ++q) {
        if (node < N) {
            b[q] = *(const half8*)&Bin[(size_t)node * DIM + q * 32 + quad * 8];
        } else {
            b[q] = half8{0, 0, 0, 0, 0, 0, 0, 0};
        }
    }

    floatx4 acc[8];
#pragma unroll
    for (int c = 0; c < 8; ++c) acc[c] = floatx4{0.f, 0.f, 0.f, 0.f};
    __syncthreads();   // lsum zeros visible before any atomic below

#pragma unroll
    for (int c = 0; c < 8; ++c) {
#pragma unroll
        for (int q = 0; q < 4; ++q) {
            half8 a = *(const half8*)&Wt[(size_t)(c * 16 + l16) * DIM + q * 32 + quad * 8];
            acc[c] = __builtin_amdgcn_mfma_f32_16x16x32_f16(a, b[q], acc[c], 0, 0, 0);
        }
    }

    int g = gid[nodec];
    int g0b = gid[r0];                          // r0 < N for every block
    int gEb = gid[min(r0 + 63, N - 1)];
    bool ldsPath = (gEb - g0b) < PBINS;         // block spans < PBINS graphs
    int gF = __shfl(g, 0);                      // graph of wave-tile node 0
    int gL = __shfl(g, 15);                     // graph of wave-tile node 15
    bool uni = (gF == gL);                      // wave-uniform
    float valid = (node < N) ? 1.0f : 0.0f;     // zero padded-node contribution

#pragma unroll
    for (int c = 0; c < 8; ++c) {
        float4 b4 = *(const float4*)&bias[c * 16 + quad * 4];
        float bv[4] = {b4.x, b4.y, b4.z, b4.w};
#pragma unroll
        for (int r = 0; r < 4; ++r) {
            float v = fmaxf(acc[c][r] + bv[r], 0.0f) * valid;
            int f = c * 16 + quad * 4 + r;
            if (ldsPath) {
                if (uni) {
                    v += __shfl_xor(v, 1);
                    v += __shfl_xor(v, 2);
                    v += __shfl_xor(v, 4);
                    v += __shfl_xor(v, 8);      // sum over the 16 nodes of the tile
                    if (l16 == 0) atomicAdd(&lsum[(gF - g0b) * DIM + f], v);
                } else {
                    if (node < N) atomicAdd(&lsum[(g - g0b) * DIM + f], v);
                }
            } else {
                if (node < N) atomicAdd(&gsum[(size_t)g * DIM + f], v);
            }
        }
    }
    __syncthreads();
    if (ldsPath) {
        int ng = gEb - g0b + 1;
        for (int i = tid; i < ng * DIM; i += 256) {
            float sv = lsum[i];
            if (sv != 0.0f) atomicAdd(&gsum[(size_t)g0b * DIM + i], sv);
        }
    }

    // ---- last-block finalize
    __threadfence();
    __syncthreads();
    if (tid == 0) lastFlag = (atomicAdd(done, 1) == (int)gridDim.x - 1) ? 1 : 0;
    __syncthreads();
    if (lastFlag) {
        __threadfence();
        for (int i = tid; i < GRAPHS * DIM; i += 256) {
            int gg = i >> 7;
            int lo = 0, hi = N;                 // lower_bound(gg)
            while (lo < hi) { int m = (lo + hi) >> 1; if (gid[m] < gg) lo = m + 1; else hi = m; }
            int lo2 = lo, hi2 = N;              // lower_bound(gg+1)
            while (lo2 < hi2) { int m = (lo2 + hi2) >> 1; if (gid[m] < gg + 1) lo2 = m + 1; else hi2 = m; }
            float c = fmaxf((float)(lo2 - lo), 1.0f);
            out[i] = gsum[i] / c;
        }
    }
}

// ---------------------------------------------------------------- launch
extern "C" void kernel_launch(void* const* d_in, const int* in_sizes, int n_in,
                              void* d_out, int out_size, void* d_ws, size_t ws_size,
                              hipStream_t stream) {
    const float* h   = (const float*)d_in[0];
    const int*   src = (const int*)d_in[1];
    const int*   dst = (const int*)d_in[2];
    const int*   gid = (const int*)d_in[3];
    const float* W1  = (const float*)d_in[4];
    const float* b1  = (const float*)d_in[5];
    const float* W2  = (const float*)d_in[6];
    const float* b2  = (const float*)d_in[7];
    const float* W3  = (const float*)d_in[8];
    const float* b3  = (const float*)d_in[9];

    const int N = in_sizes[0] / DIM;   // 50000
    const int E = in_sizes[1];         // 600000
    const int G = GRAPHS;
    float* out = (float*)d_out;
    (void)G;

    char* ws = (char*)d_ws;
    size_t off = 0;
    auto alloc = [&](size_t bytes) -> void* {
        void* p = ws + off;
        off += (bytes + 255) & ~(size_t)255;
        return p;
    };
    const int nb = (N + 255) / 256;    // 196
    uint2* Ah0     = (uint2*)alloc((size_t)N * DIM * 2);  // fp16 gather operand (ping)
    uint2* Ah1     = (uint2*)alloc((size_t)N * DIM * 2);  // fp16 pong
    uint2* Bh      = (uint2*)alloc((size_t)N * DIM * 2);  // agg output (fp16)
    _Float16* Wt1  = (_Float16*)alloc((size_t)DIM * DIM * 2);
    _Float16* Wt2  = (_Float16*)alloc((size_t)DIM * DIM * 2);
    _Float16* Wt3  = (_Float16*)alloc((size_t)DIM * DIM * 2);
    float* ns      = (float*)alloc((size_t)N * 4);
    float* nd      = (float*)alloc((size_t)N * 4);
    int*   inc     = (int*)alloc((size_t)N * 4);
    unsigned* partial = (unsigned*)alloc((size_t)2 * HR2 * HIST_S * LW2 * 4);   // 12.8 MB
    int*   cur     = (int*)alloc((size_t)FILL_R * HIST_S * NPR * 4);            // 12.8 MB
    int*   row_ptr = (int*)alloc((size_t)(N + 1) * 4);
    int*   csr     = (int*)alloc((size_t)E * 4);
    float* gsum    = (float*)alloc((size_t)GRAPHS * DIM * 4);
    int*   bsum    = (int*)alloc((size_t)nb * 4);
    int*   done    = (int*)alloc(256);

    // degrees via LDS histograms (2 ranges x 25K nodes, 50KB LDS, 256 blocks)
    k_hist<<<2 * HR2 * HIST_S, 256, 0, stream>>>(src, dst, partial, E);
    // merge -> ns/nd/inc + per-block sums
    k_hist_merge<<<2 * nb, 256, 0, stream>>>(partial, ns, nd, inc, bsum, N);
    // row_ptr + cursors (FILL_R windows) + gsum/done zero + prep (folded)
    int prepBlocks = (N * 32 + 3 * 16384 + 255) / 256;   // 6442
    k_scan_prep<<<nb + prepBlocks, 256, 0, stream>>>(inc, bsum, partial, row_ptr, cur,
                                                     gsum, done, (const float4*)h, ns,
                                                     Ah0, W1, W2, W3, Wt1, Wt2, Wt3, N);
    k_fill2<<<FILL_R * HIST_S, 256, 0, stream>>>(src, dst, cur, csr, E);

    int aggBlocks  = (N * 64 + 255) / 256;
    int gemmBlocks = (N + 63) / 64;

    // layer 1
    k_agg<<<aggBlocks, 256, 0, stream>>>((const uint4*)Ah0, row_ptr, csr, nd, (uint4*)Bh, N);
    k_gemm_t<true><<<gemmBlocks, 256, 0, stream>>>((const _Float16*)Bh, Wt1, b1, ns, (_Float16*)Ah1, N);
    // layer 2
    k_agg<<<aggBlocks, 256, 0, stream>>>((const uint4*)Ah1, row_ptr, csr, nd, (uint4*)Bh, N);
    k_gemm_t<true><<<gemmBlocks, 256, 0, stream>>>((const _Float16*)Bh, Wt2, b2, ns, (_Float16*)Ah0, N);
    // layer 3: agg + GEMM + pooling + last-block finalize
    k_agg<<<aggBlocks, 256, 0, stream>>>((const uint4*)Ah0, row_ptr, csr, nd, (uint4*)Bh, N);
    k_gemm_pool<<<gemmBlocks, 256, 0, stream>>>((const _Float16*)Bh, Wt3, b3, gid, gsum,
                                                done, out, N);
}

// Round 8
// 305.337 us; speedup vs baseline: 1.6441x; 1.6441x over previous
//
#include <hip/hip_runtime.h>
#include <hip/hip_fp16.h>

// GraphEmbedding2: 3-layer GCN (DGL GraphConv, norm='both') + per-graph mean pooling.
// N=50000 nodes, E=600000 edges, d=128, G=64 graphs.
// fp16 gather operands (R6); LDS-histogram degrees + LDS-cursor CSR fill (R5/R8);
// MFMA fp16-in/fp32-acc transposed roles (R9/R15); pool-fused layer 3 (R15);
// 32-edge-round agg (R17); prep folded into scan (R20); HR2=2 hist ranges (R21a).
// R22: REVERT R21b last-block-ticket finalize (FAILED +196us: k_gemm_pool 242us real —
// __threadfence() is device-scope on gfx950's non-coherent per-XCD L2s -> per-block
// L2-writeback ~0.3us x 782 blocks serialized. NEVER put threadfence in a per-block
// epilogue; a 2us standalone dispatch is cheaper). k_finalize restored. HR2 hist kept
// (edge arrays read 2x not 4x; independent of the regression).
// Agg wall (3x ~38us) is line-service-capped: R17 doubled lines-in-flight -> neutral;
// R18 locality slicing -> negative; ~4 TB/s random-64B-line service is the HW number.
// Reverted-for-cause: R7/R16 fusion, R11 range passes, R13 HIST_S=32, R18 quartered
// gather, R19 global-atomic CSR build (k_deg 50us), R21b threadfence finalize.

#define DIM 128
#define GRAPHS 64

typedef _Float16 half8 __attribute__((ext_vector_type(8)));
typedef _Float16 half4 __attribute__((ext_vector_type(4)));
typedef float floatx4 __attribute__((ext_vector_type(4)));

// hist/merge layout (R21a): 2 ranges x 25000 nodes
#define HR2 2
#define NP2 25000
#define LW2 (NP2 / 2)      // 12500 u32 words, 50 KB LDS
#define HIST_S 64
// cursor/fill layout (unchanged): 4 windows x 12500 nodes
#define FILL_R 4
#define NPR 12500

__global__ __launch_bounds__(256) void k_hist(const int* __restrict__ src,
                                              const int* __restrict__ dst,
                                              unsigned* __restrict__ partial, int E) {
    __shared__ __align__(16) unsigned hist[LW2];
    int b = blockIdx.x;
    int a = b / (HR2 * HIST_S);          // 0: src, 1: dst
    int r = (b / HIST_S) % HR2;          // node range (25000 wide)
    int s = b % HIST_S;                  // edge slice
    const int* arr = a ? dst : src;
    for (int i = threadIdx.x; i < LW2; i += 256) hist[i] = 0;
    __syncthreads();
    int chunk = (E + HIST_S - 1) / HIST_S;
    int e0 = s * chunk;
    int e1 = min(e0 + chunk, E);
    unsigned base = (unsigned)(r * NP2);
    for (int i = e0 + threadIdx.x; i < e1; i += 256) {
        unsigned n = (unsigned)arr[i] - base;
        if (n < NP2) atomicAdd(&hist[n >> 1], 1u << ((n & 1) * 16));
    }
    __syncthreads();
    uint2* outp = (uint2*)(partial + ((size_t)(a * HR2 + r) * HIST_S + s) * LW2);
    const uint2* h2 = (const uint2*)hist;
    for (int i = threadIdx.x; i < LW2 / 2; i += 256) outp[i] = h2[i];
}

// ---------------------------------------------------------------- merge + block sums
// Blocks [0, nb): dst — nd, inc, per-256-node bsum. Blocks [nb, 2nb): src — ns.
__global__ __launch_bounds__(256) void k_hist_merge(const unsigned* __restrict__ partial,
                                                    float* __restrict__ ns,
                                                    float* __restrict__ nd,
                                                    int* __restrict__ inc,
                                                    int* __restrict__ bsum, int N) {
    __shared__ int sred[256];
    int nb = (N + 255) / 256;
    int isDst = (blockIdx.x < nb) ? 1 : 0;
    int cb = isDst ? blockIdx.x : blockIdx.x - nb;
    int n = cb * 256 + threadIdx.x;
    int deg = 0;
    if (n < N) {
        int a = isDst ? 1 : 0;
        int r = n / NP2;
        int w = (n % NP2) >> 1;
        int field = (n & 1) * 16;
        const unsigned* p = partial + ((size_t)(a * HR2 + r) * HIST_S) * LW2 + w;
        unsigned sum = 0;
#pragma unroll
        for (int s = 0; s < HIST_S; ++s) sum += p[(size_t)s * LW2];
        deg = (int)((sum >> field) & 0xFFFFu);
        float nrm = rsqrtf(fmaxf((float)deg, 1.0f));
        if (isDst) { nd[n] = nrm; inc[n] = deg; }
        else       { ns[n] = nrm; }
    }
    if (isDst) {
        sred[threadIdx.x] = deg;
        __syncthreads();
        for (int off = 128; off > 0; off >>= 1) {
            if (threadIdx.x < off) sred[threadIdx.x] += sred[threadIdx.x + off];
            __syncthreads();
        }
        if (threadIdx.x == 0) bsum[cb] = sred[0];
    }
}

// ---------------------------------------------------------------- scan + cursors + prep (folded)
// Blocks [0, nb): block-sum scan -> row_ptr scan -> per-(window,slice) cursors;
// block 0 zeroes gsum. Blocks [nb, nb+prepBlocks): prep role.
__global__ __launch_bounds__(256) void k_scan_prep(
    const int* __restrict__ inc, const int* __restrict__ bsum,
    const unsigned* __restrict__ partial, int* __restrict__ row_ptr,
    int* __restrict__ cur, float* __restrict__ gsum,
    const float4* __restrict__ h, const float* __restrict__ ns,
    uint2* __restrict__ A, const float* __restrict__ W1,
    const float* __restrict__ W2, const float* __restrict__ W3,
    _Float16* __restrict__ Wt1, _Float16* __restrict__ Wt2,
    _Float16* __restrict__ Wt3, int N) {
    __shared__ int sb[256];
    __shared__ int s[256];
    __shared__ int exs[256];
    int nb = (N + 255) / 256;
    int t = threadIdx.x;

    if (blockIdx.x >= nb) {
        // ---- prep role
        int i = (blockIdx.x - nb) * 256 + t;
        int nf4 = N * 32;
        if (i < nf4) {
            int n = i >> 5;
            float sc = ns[n];
            float4 v = h[i];
            __half2 p0 = __floats2half2_rn(v.x * sc, v.y * sc);
            __half2 p1 = __floats2half2_rn(v.z * sc, v.w * sc);
            uint2 o;
            o.x = *(unsigned*)&p0;
            o.y = *(unsigned*)&p1;
            A[i] = o;
        } else {
            int j = i - nf4;               // 0 .. 3*16384-1
            if (j < 3 * 16384) {
                int which = j >> 14;
                int local = j & 16383;
                int k = local >> 7;
                int n = local & 127;
                const float* W = (which == 0) ? W1 : (which == 1) ? W2 : W3;
                _Float16* Wt = (which == 0) ? Wt1 : (which == 1) ? Wt2 : Wt3;
                Wt[(size_t)n * DIM + k] = (_Float16)W[local];
            }
        }
        return;
    }

    // ---- scan role: phase 0 — exclusive-scan block sums
    int bv = (t < nb) ? bsum[t] : 0;
    sb[t] = bv;
    __syncthreads();
    for (int off = 1; off < 256; off <<= 1) {
        int u = (t >= off) ? sb[t - off] : 0;
        __syncthreads();
        sb[t] += u;
        __syncthreads();
    }
    int excl = sb[t] - bv;
    __syncthreads();
    sb[t] = excl;
    __syncthreads();
    int blockBase = sb[blockIdx.x];

    // phase A: local scan of inc
    int B = blockIdx.x * 256;
    int i = B + t;
    int v = (i < N) ? inc[i] : 0;
    s[t] = v;
    __syncthreads();
    for (int off = 1; off < 256; off <<= 1) {
        int u = (t >= off) ? s[t - off] : 0;
        __syncthreads();
        s[t] += u;
        __syncthreads();
    }
    int ex = blockBase + s[t] - v;  // global exclusive prefix
    exs[t] = ex;
    if (i < N) row_ptr[i] = ex;
    if (i == N - 1) row_ptr[N] = ex + v;
    if (blockIdx.x == 0) {
        for (int j = t; j < GRAPHS * DIM; j += 256) gsum[j] = 0.0f;
    }
    __syncthreads();

    // phase B: per-(window,slice) cursors. dst histogram lives in HR2 layout;
    // cursors use FILL_R x NPR windows (fill2's layout). Per-node counters decouple.
    if (t < 128) {
        int n0 = B + 2 * t;
        if (n0 < N) {
            int r2 = n0 / NP2;
            int w2 = (n0 % NP2) >> 1;
            const unsigned* p = partial + ((size_t)(HR2 + r2) * HIST_S) * LW2 + w2;
            int r4 = n0 / NPR;
            int wf = (n0 % NPR) >> 1;
            int run0 = exs[2 * t];
            int run1 = exs[2 * t + 1];
            int* c = cur + (size_t)r4 * HIST_S * NPR + 2 * wf;
#pragma unroll
            for (int sl = 0; sl < HIST_S; ++sl) {
                c[(size_t)sl * NPR + 0] = run0;
                c[(size_t)sl * NPR + 1] = run1;
                unsigned hv = p[(size_t)sl * LW2];
                run0 += (int)(hv & 0xFFFFu);
                run1 += (int)(hv >> 16);
            }
        }
    }
}

// ---------------------------------------------------------------- CSR fill (LDS cursors)
__global__ __launch_bounds__(256) void k_fill2(const int* __restrict__ src,
                                               const int* __restrict__ dst,
                                               const int* __restrict__ cur,
                                               int* __restrict__ csr, int E) {
    __shared__ __align__(16) int lcur[NPR];   // 50 KB
    int r = blockIdx.x / HIST_S;
    int s = blockIdx.x % HIST_S;
    const int4* cs4 = (const int4*)(cur + (size_t)(r * HIST_S + s) * NPR);
    int4* l4 = (int4*)lcur;
    for (int i = threadIdx.x; i < NPR / 4; i += 256) l4[i] = cs4[i];
    __syncthreads();
    int chunk = (E + HIST_S - 1) / HIST_S;
    int e0 = s * chunk;
    int e1 = min(e0 + chunk, E);
    unsigned base = (unsigned)(r * NPR);
    for (int i = e0 + threadIdx.x; i < e1; i += 256) {
        unsigned d = (unsigned)dst[i] - base;
        if (d < NPR) {
            int p = atomicAdd(&lcur[d], 1);   // LDS atomic
            csr[p] = src[i];
        }
    }
}

// ---------------------------------------------------------------- aggregation (R17 form)
// One wave per node (50K waves). 32-edge rounds: 16 lanes x 16B cover one 256B row ->
// 4 rows per load instruction, 8 loads = 32 edges in flight. Indices: 1 VMEM load of
// 32 idx by lane&31 + shfl broadcast. Epilogue: shfl_xor(16/32) reduce, uint4 stores.
__global__ __launch_bounds__(256) void k_agg(const uint4* __restrict__ A,
                                             const int* __restrict__ row_ptr,
                                             const int* __restrict__ csr,
                                             const float* __restrict__ nd,
                                             uint4* __restrict__ Bh, int N) {
    int gtid = blockIdx.x * blockDim.x + threadIdx.x;
    int node = gtid >> 6;
    int lane = threadIdx.x & 63;
    if (node >= N) return;
    int e0 = row_ptr[node];
    int e1 = row_ptr[node + 1];
    int grp = lane >> 4;     // edge sub-slot within a 4-edge load row-group
    int l16 = lane & 15;     // 16-byte slot within 256B row
    float acc[8];
#pragma unroll
    for (int k = 0; k < 8; ++k) acc[k] = 0.0f;

    for (int base = e0; base < e1; base += 32) {
        int vl = csr[min(base + (lane & 31), e1 - 1)];   // lanes 0-31 hold 32 indices
        uint4 u[8];
#pragma unroll
        for (int j = 0; j < 8; ++j) {
            int idx = __shfl(vl, 4 * j + grp);
            u[j] = A[(size_t)idx * 16 + l16];
        }
#pragma unroll
        for (int j = 0; j < 8; ++j) {
            if (base + 4 * j + grp < e1) {
                __half2 h0 = *(__half2*)&u[j].x;
                __half2 h1 = *(__half2*)&u[j].y;
                __half2 h2 = *(__half2*)&u[j].z;
                __half2 h3 = *(__half2*)&u[j].w;
                float2 f0 = __half22float2(h0);
                float2 f1 = __half22float2(h1);
                float2 f2 = __half22float2(h2);
                float2 f3 = __half22float2(h3);
                acc[0] += f0.x; acc[1] += f0.y;
                acc[2] += f1.x; acc[3] += f1.y;
                acc[4] += f2.x; acc[5] += f2.y;
                acc[6] += f3.x; acc[7] += f3.y;
            }
        }
    }

#pragma unroll
    for (int k = 0; k < 8; ++k) {
        float v = acc[k];
        v += __shfl_xor(v, 16);
        v += __shfl_xor(v, 32);
        acc[k] = v;
    }

    if (grp == 0) {
        float s = nd[node];
        __half2 p0 = __floats2half2_rn(acc[0] * s, acc[1] * s);
        __half2 p1 = __floats2half2_rn(acc[2] * s, acc[3] * s);
        __half2 p2 = __floats2half2_rn(acc[4] * s, acc[5] * s);
        __half2 p3 = __floats2half2_rn(acc[6] * s, acc[7] * s);
        uint4 o;
        o.x = *(unsigned*)&p0;
        o.y = *(unsigned*)&p1;
        o.z = *(unsigned*)&p2;
        o.w = *(unsigned*)&p3;
        Bh[(size_t)node * 16 + l16] = o;
    }
}

// ---------------------------------------------------------------- GEMM on matrix cores (R15 transposed roles)
template <bool SCALE_NS>
__global__ __launch_bounds__(256) void k_gemm_t(
    const _Float16* __restrict__ Bin, const _Float16* __restrict__ Wt,
    const float* __restrict__ bias, const float* __restrict__ ns,
    _Float16* __restrict__ Xout, int N) {
    int tid = threadIdx.x;
    int wave = tid >> 6;
    int lane = tid & 63;
    int quad = lane >> 4;
    int l16 = lane & 15;
    int node = blockIdx.x * 64 + wave * 16 + l16;

    half8 b[4];
#pragma unroll
    for (int q = 0; q < 4; ++q) {
        if (node < N) {
            b[q] = *(const half8*)&Bin[(size_t)node * DIM + q * 32 + quad * 8];
        } else {
            b[q] = half8{0, 0, 0, 0, 0, 0, 0, 0};
        }
    }

    floatx4 acc[8];
#pragma unroll
    for (int c = 0; c < 8; ++c) acc[c] = floatx4{0.f, 0.f, 0.f, 0.f};

#pragma unroll
    for (int c = 0; c < 8; ++c) {
#pragma unroll
        for (int q = 0; q < 4; ++q) {
            half8 a = *(const half8*)&Wt[(size_t)(c * 16 + l16) * DIM + q * 32 + quad * 8];
            acc[c] = __builtin_amdgcn_mfma_f32_16x16x32_f16(a, b[q], acc[c], 0, 0, 0);
        }
    }

    if (node < N) {
        float s = SCALE_NS ? ns[node] : 1.0f;
#pragma unroll
        for (int c = 0; c < 8; ++c) {
            float4 b4 = *(const float4*)&bias[c * 16 + quad * 4];
            half4 o;
            o[0] = (_Float16)(fmaxf(acc[c][0] + b4.x, 0.0f) * s);
            o[1] = (_Float16)(fmaxf(acc[c][1] + b4.y, 0.0f) * s);
            o[2] = (_Float16)(fmaxf(acc[c][2] + b4.z, 0.0f) * s);
            o[3] = (_Float16)(fmaxf(acc[c][3] + b4.w, 0.0f) * s);
            *(half4*)&Xout[(size_t)node * DIM + c * 16 + quad * 4] = o;
        }
    }
}

// ---------------------------------------------------------------- layer-3 GEMM fused with pooling
// Same MFMA body as k_gemm_t<false>, epilogue pools directly from fp32 acc.
#define PBINS 8
__global__ __launch_bounds__(256) void k_gemm_pool(
    const _Float16* __restrict__ Bin, const _Float16* __restrict__ Wt,
    const float* __restrict__ bias, const int* __restrict__ gid,
    float* __restrict__ gsum, int N) {
    __shared__ float lsum[PBINS * DIM];   // 4 KB
    int tid = threadIdx.x;
    for (int i = tid; i < PBINS * DIM; i += 256) lsum[i] = 0.0f;
    int wave = tid >> 6;
    int lane = tid & 63;
    int quad = lane >> 4;
    int l16 = lane & 15;
    int r0 = blockIdx.x * 64;
    int node = r0 + wave * 16 + l16;
    int nodec = min(node, N - 1);

    half8 b[4];
#pragma unroll
    for (int q = 0; q < 4; ++q) {
        if (node < N) {
            b[q] = *(const half8*)&Bin[(size_t)node * DIM + q * 32 + quad * 8];
        } else {
            b[q] = half8{0, 0, 0, 0, 0, 0, 0, 0};
        }
    }

    floatx4 acc[8];
#pragma unroll
    for (int c = 0; c < 8; ++c) acc[c] = floatx4{0.f, 0.f, 0.f, 0.f};
    __syncthreads();   // lsum zeros visible before any atomic below

#pragma unroll
    for (int c = 0; c < 8; ++c) {
#pragma unroll
        for (int q = 0; q < 4; ++q) {
            half8 a = *(const half8*)&Wt[(size_t)(c * 16 + l16) * DIM + q * 32 + quad * 8];
            acc[c] = __builtin_amdgcn_mfma_f32_16x16x32_f16(a, b[q], acc[c], 0, 0, 0);
        }
    }

    int g = gid[nodec];
    int g0b = gid[r0];                          // r0 < N for every block
    int gEb = gid[min(r0 + 63, N - 1)];
    bool ldsPath = (gEb - g0b) < PBINS;         // block spans < PBINS graphs
    int gF = __shfl(g, 0);                      // graph of wave-tile node 0
    int gL = __shfl(g, 15);                     // graph of wave-tile node 15
    bool uni = (gF == gL);                      // wave-uniform
    float valid = (node < N) ? 1.0f : 0.0f;     // zero padded-node contribution

#pragma unroll
    for (int c = 0; c < 8; ++c) {
        float4 b4 = *(const float4*)&bias[c * 16 + quad * 4];
        float bv[4] = {b4.x, b4.y, b4.z, b4.w};
#pragma unroll
        for (int r = 0; r < 4; ++r) {
            float v = fmaxf(acc[c][r] + bv[r], 0.0f) * valid;
            int f = c * 16 + quad * 4 + r;
            if (ldsPath) {
                if (uni) {
                    v += __shfl_xor(v, 1);
                    v += __shfl_xor(v, 2);
                    v += __shfl_xor(v, 4);
                    v += __shfl_xor(v, 8);      // sum over the 16 nodes of the tile
                    if (l16 == 0) atomicAdd(&lsum[(gF - g0b) * DIM + f], v);
                } else {
                    if (node < N) atomicAdd(&lsum[(g - g0b) * DIM + f], v);
                }
            } else {
                if (node < N) atomicAdd(&gsum[(size_t)g * DIM + f], v);
            }
        }
    }
    __syncthreads();
    if (ldsPath) {
        int ng = gEb - g0b + 1;
        for (int i = tid; i < ng * DIM; i += 256) {
            float sv = lsum[i];
            if (sv != 0.0f) atomicAdd(&gsum[(size_t)g0b * DIM + i], sv);
        }
    }
}

// ---------------------------------------------------------------- finalize (count via binary search)
__global__ void k_finalize(const float* __restrict__ gsum, const int* __restrict__ gid,
                           float* __restrict__ out, int N, int G) {
    int i = blockIdx.x * blockDim.x + threadIdx.x;
    if (i < G * DIM) {
        int g = i >> 7;
        int lo = 0, hi = N;                 // lower_bound(g)
        while (lo < hi) { int m = (lo + hi) >> 1; if (gid[m] < g) lo = m + 1; else hi = m; }
        int lo2 = lo, hi2 = N;              // lower_bound(g+1)
        while (lo2 < hi2) { int m = (lo2 + hi2) >> 1; if (gid[m] < g + 1) lo2 = m + 1; else hi2 = m; }
        float c = fmaxf((float)(lo2 - lo), 1.0f);
        out[i] = gsum[i] / c;
    }
}

// ---------------------------------------------------------------- launch
extern "C" void kernel_launch(void* const* d_in, const int* in_sizes, int n_in,
                              void* d_out, int out_size, void* d_ws, size_t ws_size,
                              hipStream_t stream) {
    const float* h   = (const float*)d_in[0];
    const int*   src = (const int*)d_in[1];
    const int*   dst = (const int*)d_in[2];
    const int*   gid = (const int*)d_in[3];
    const float* W1  = (const float*)d_in[4];
    const float* b1  = (const float*)d_in[5];
    const float* W2  = (const float*)d_in[6];
    const float* b2  = (const float*)d_in[7];
    const float* W3  = (const float*)d_in[8];
    const float* b3  = (const float*)d_in[9];

    const int N = in_sizes[0] / DIM;   // 50000
    const int E = in_sizes[1];         // 600000
    const int G = GRAPHS;
    float* out = (float*)d_out;

    char* ws = (char*)d_ws;
    size_t off = 0;
    auto alloc = [&](size_t bytes) -> void* {
        void* p = ws + off;
        off += (bytes + 255) & ~(size_t)255;
        return p;
    };
    const int nb = (N + 255) / 256;    // 196
    uint2* Ah0     = (uint2*)alloc((size_t)N * DIM * 2);  // fp16 gather operand (ping)
    uint2* Ah1     = (uint2*)alloc((size_t)N * DIM * 2);  // fp16 pong
    uint2* Bh      = (uint2*)alloc((size_t)N * DIM * 2);  // agg output (fp16)
    _Float16* Wt1  = (_Float16*)alloc((size_t)DIM * DIM * 2);
    _Float16* Wt2  = (_Float16*)alloc((size_t)DIM * DIM * 2);
    _Float16* Wt3  = (_Float16*)alloc((size_t)DIM * DIM * 2);
    float* ns      = (float*)alloc((size_t)N * 4);
    float* nd      = (float*)alloc((size_t)N * 4);
    int*   inc     = (int*)alloc((size_t)N * 4);
    unsigned* partial = (unsigned*)alloc((size_t)2 * HR2 * HIST_S * LW2 * 4);   // 12.8 MB
    int*   cur     = (int*)alloc((size_t)FILL_R * HIST_S * NPR * 4);            // 12.8 MB
    int*   row_ptr = (int*)alloc((size_t)(N + 1) * 4);
    int*   csr     = (int*)alloc((size_t)E * 4);
    float* gsum    = (float*)alloc((size_t)GRAPHS * DIM * 4);
    int*   bsum    = (int*)alloc((size_t)nb * 4);

    // degrees via LDS histograms (2 ranges x 25K nodes, 50KB LDS, 256 blocks)
    k_hist<<<2 * HR2 * HIST_S, 256, 0, stream>>>(src, dst, partial, E);
    // merge -> ns/nd/inc + per-block sums
    k_hist_merge<<<2 * nb, 256, 0, stream>>>(partial, ns, nd, inc, bsum, N);
    // row_ptr + cursors (FILL_R windows) + gsum zero + prep (folded)
    int prepBlocks = (N * 32 + 3 * 16384 + 255) / 256;   // 6442
    k_scan_prep<<<nb + prepBlocks, 256, 0, stream>>>(inc, bsum, partial, row_ptr, cur,
                                                     gsum, (const float4*)h, ns, Ah0,
                                                     W1, W2, W3, Wt1, Wt2, Wt3, N);
    k_fill2<<<FILL_R * HIST_S, 256, 0, stream>>>(src, dst, cur, csr, E);

    int aggBlocks  = (N * 64 + 255) / 256;
    int gemmBlocks = (N + 63) / 64;

    // layer 1
    k_agg<<<aggBlocks, 256, 0, stream>>>((const uint4*)Ah0, row_ptr, csr, nd, (uint4*)Bh, N);
    k_gemm_t<true><<<gemmBlocks, 256, 0, stream>>>((const _Float16*)Bh, Wt1, b1, ns, (_Float16*)Ah1, N);
    // layer 2
    k_agg<<<aggBlocks, 256, 0, stream>>>((const uint4*)Ah1, row_ptr, csr, nd, (uint4*)Bh, N);
    k_gemm_t<true><<<gemmBlocks, 256, 0, stream>>>((const _Float16*)Bh, Wt2, b2, ns, (_Float16*)Ah0, N);
    // layer 3: agg + GEMM fused with pooling
    k_agg<<<aggBlocks, 256, 0, stream>>>((const uint4*)Ah0, row_ptr, csr, nd, (uint4*)Bh, N);
    k_gemm_pool<<<gemmBlocks, 256, 0, stream>>>((const _Float16*)Bh, Wt3, b3, gid, gsum, N);

    k_finalize<<<(G * DIM + 255) / 256, 256, 0, stream>>>(gsum, gid, out, N, G);
}